// Round 17
// baseline (135.126 us; speedup 1.0000x reference)
//
#include <hip/hip_runtime.h>
#include <hip/hip_cooperative_groups.h>
#include <cmath>

namespace cg = cooperative_groups;

typedef __bf16 bf16x4v __attribute__((ext_vector_type(4)));
typedef __bf16 bf16x8 __attribute__((ext_vector_type(8)));
typedef float f32x4 __attribute__((ext_vector_type(4)));

namespace {
constexpr int kN = 16, kC = 64, kT = 512, kV = 25, kS = 3, kO = 64;
constexpr int kTV = kT * kV;  // 12800
// ws layout (bytes): xm f32[25600 f] | afrag[48][8192][16] | w3f[3][512][16] | x_bf bf16
constexpr size_t WS_AFRAG = 102400;
constexpr size_t WS_W3F = WS_AFRAG + (size_t)48 * 131072;  // 6,393,856
constexpr size_t WS_XBF = WS_W3F + 3 * 8192;               // 6,418,432
}  // namespace

// X3s: bf16 [c 64][t 16][u 32] swizzled with ((c^t)&7)<<4 (XOR bits 4-6 ONLY:
// >= 16-byte read granule). Bytes [0, 65536). w3_lds (8KB, current s) at 65536.
__device__ __forceinline__ int swzB16(int c, int t, int ubyte) {
  return (c << 10) + (((t << 6) + ubyte) ^ ((((c ^ t) & 7)) << 4));
}

// Single fused cooperative kernel: A(k1) -> grid.sync -> B(k2) -> grid.sync -> C(k3 x2)
__global__ __launch_bounds__(512) void k_fused(
    const float* __restrict__ x, const float* __restrict__ Ag,
    const float* __restrict__ alpha, const float* __restrict__ w1,
    const float* __restrict__ b1, const float* __restrict__ w2,
    const float* __restrict__ b2, const float* __restrict__ w3,
    const float* __restrict__ b3, const float* __restrict__ w4,
    const float* __restrict__ b4, const int* __restrict__ sparse,
    unsigned char* __restrict__ ws, float* __restrict__ y) {
  cg::grid_group grid = cg::this_grid();
  extern __shared__ __align__(16) unsigned char smem[];  // 73728
  const int b = blockIdx.x;  // 0..255
  const int tid = threadIdx.x;

  float* xm = (float*)ws;
  __bf16* xbf = (__bf16*)(ws + WS_XBF);

  // ================= PHASE A: x f32 -> x_bf bf16 + mean (4 columns/block) ====
  {
    const int half = tid >> 8;   // 0/1: two columns in parallel
    const int lt = tid & 255;
    float* part = (float*)smem + half * 1000;  // [250][4] each
#pragma unroll
    for (int pr = 0; pr < 2; ++pr) {
      const int colid = b * 4 + pr * 2 + half;  // (n*64+c) column
      const float4* xg4 = (const float4*)(x + (size_t)colid * kTV);
      bf16x4v* xb4 = (bf16x4v*)(xbf + (size_t)colid * kTV);
      if (lt < 250) {
        float a0 = 0.f, a1 = 0.f, a2 = 0.f, a3 = 0.f;
        for (int j = lt; j < 3200; j += 250) {  // j%250==lt -> const v-phase
          float4 v = xg4[j];
          a0 += v.x; a1 += v.y; a2 += v.z; a3 += v.w;
          bf16x4v o;
          o[0] = (__bf16)v.x; o[1] = (__bf16)v.y;
          o[2] = (__bf16)v.z; o[3] = (__bf16)v.w;
          xb4[j] = o;
        }
        part[lt * 4 + 0] = a0; part[lt * 4 + 1] = a1;
        part[lt * 4 + 2] = a2; part[lt * 4 + 3] = a3;
      }
      __syncthreads();
      if (lt < 25) {
        float s = 0.f;
#pragma unroll
        for (int r = 0; r < 4; ++r) {
          int q = ((lt - r + 25) % 25) * 19 % 25;
#pragma unroll
          for (int p = 0; p < 10; ++p) s += part[(q + 25 * p) * 4 + r];
        }
        xm[colid * 25 + lt] = s * (1.f / 512.f);
      }
      __syncthreads();
    }
  }
  grid.sync();

  // ================= PHASE B: attention -> a_frag + w3 frags (blocks 0..191) ==
  if (b < 192) {
    const float thr = (float)sparse[0];
    const int s = b >> 6, n = (b >> 2) & 15, q = b & 3;
    float* xm_l = (float*)smem;              // 1600
    float* x1_l = xm_l + 1600;               // 200
    float* x2_l = x1_l + 200;                // 200
    float* att_l = x2_l + 200;               // 5000
    float* attsum_l = att_l + 5000;          // 200
    float* ag_l = attsum_l + 200;            // 625
    float* acs_l = ag_l + 625;               // 25
    float* w4_l = acs_l + 25;                // 512  (total 8362 f = 33.4 KB)
    for (int i = tid; i < 1600; i += 512) xm_l[i] = xm[n * 1600 + i];
    for (int i = tid; i < 512; i += 512) {
      float w = w4[s * 512 + i];
      w4_l[i] = (fabsf(w) > thr) ? w : 0.f;
    }
    for (int i = tid; i < 625; i += 512) ag_l[i] = Ag[s * 625 + i];
    __syncthreads();
    for (int i = tid; i < 400; i += 512) {
      int which = i / 200, idx = i % 200, r = idx / 25, u = idx % 25;
      const float* wrow = (which == 0 ? w1 : w2) + (s * 8 + r) * 64;
      float acc = 0.f;
      for (int cc = 0; cc < 64; ++cc) {
        float w = wrow[cc];
        w = (fabsf(w) > thr) ? w : 0.f;
        acc += w * xm_l[cc * 25 + u];
      }
      acc += (which == 0 ? b1 : b2)[s * 8 + r];
      if (which == 0) x1_l[idx] = acc;
      else x2_l[idx] = acc;
    }
    __syncthreads();
    for (int i = tid; i < 8 * 625; i += 512) {
      int r = i / 625, uv = i % 625, u = uv / 25, v = uv % 25;
      att_l[i] = tanhf(x1_l[r * 25 + u] - x2_l[r * 25 + v]);
    }
    __syncthreads();
    if (tid < 200) {
      int r = tid / 25, v = tid % 25;
      float sum = 0.f;
      for (int u = 0; u < 25; ++u) sum += att_l[r * 625 + u * 25 + v];
      attsum_l[tid] = sum;
    } else if (tid < 225) {
      int v = tid - 200;
      float sum = 0.f;
      for (int u = 0; u < 25; ++u) sum += ag_l[u * 25 + v];
      acs_l[v] = sum;
    }
    __syncthreads();
    const float al = alpha[0];
    // a_ext[c][u][v]: u<25 -> a ; u==25 -> colsum(a) (bias-fold) ; u>25 -> 0
    unsigned char* afrag = ws + WS_AFRAG + (size_t)(s * 16 + n) * 131072;
    for (int slot = q * 2048 + tid; slot < (q + 1) * 2048; slot += 512) {
      int c = slot >> 7, vt = (slot >> 6) & 1, l = slot & 63;
      int v = vt * 16 + (l & 15), g = l >> 4;
      bf16x8 out;
      if (v < 25) {
        float b4v = b4[s * 64 + c];
#pragma unroll
        for (int j = 0; j < 8; ++j) {
          int u = g * 8 + j;
          float val = 0.f;
          if (u < 25) {
            float acc = 0.f;
#pragma unroll
            for (int r = 0; r < 8; ++r)
              acc += w4_l[c * 8 + r] * att_l[r * 625 + u * 25 + v];
            val = al * (acc + b4v) + ag_l[u * 25 + v];
          } else if (u == 25) {
            float acc = 0.f;
#pragma unroll
            for (int r = 0; r < 8; ++r)
              acc += w4_l[c * 8 + r] * attsum_l[r * 25 + v];
            val = al * acc + 25.f * al * b4v + acs_l[v];
          }
          out[j] = (__bf16)val;
        }
      } else {
#pragma unroll
        for (int j = 0; j < 8; ++j) out[j] = (__bf16)0.f;
      }
      *(bf16x8*)(afrag + (size_t)slot * 16) = out;
    }
    // w3 frags (B-operand layout [o][c'])
    if (n == 0 && tid < 128) {
      unsigned char* w3f = ws + WS_W3F + (size_t)s * 8192;
      int slot = q * 128 + tid;
      int ot = slot >> 7, ks = (slot >> 6) & 1, l = slot & 63;
      int o = ot * 16 + (l & 15), g = l >> 4;
      bf16x8 out;
#pragma unroll
      for (int j = 0; j < 8; ++j) {
        int cp = ks * 32 + g * 8 + j;
        float w = w3[(s * 64 + o) * 64 + cp];
        out[j] = (__bf16)((fabsf(w) > thr) ? w : 0.f);
      }
      *(bf16x8*)(w3f + slot * 16) = out;
    }
  }
  grid.sync();

  // ================= PHASE C: two k3 tb-units per block =====================
  const int w = tid >> 6, l = tid & 63, g = l >> 4, l15 = l & 15;
  const int n = b >> 4;
  const unsigned char* afrag = ws + WS_AFRAG;
  const unsigned char* w3f = ws + WS_W3F;
  const __bf16* xbp = xbf + (size_t)n * kC * kTV;

  for (int unit = 0; unit < 2; ++unit) {
    const int tb = ((b & 15) << 1) | unit;
    __syncthreads();  // prev unit's epilogue LDS reads done
    // zero X3s pad u=26..31 (3 u32 per (c,t))
    for (int idx = tid; idx < 3072; idx += 512) {
      int pair = idx / 3, k = idx % 3;
      int c = pair >> 4, t = pair & 15;
      *(unsigned int*)(smem + swzB16(c, t, 52 + 4 * k)) = 0u;
    }
    // A-frags of X from x_bf: lane m=u, k=c'; t = 2w+(cti>>1). s-invariant.
    bf16x8 xa[4][2];
#pragma unroll
    for (int cti = 0; cti < 4; ++cti)
#pragma unroll
      for (int kf = 0; kf < 2; ++kf)
#pragma unroll
        for (int j = 0; j < 8; ++j) xa[cti][kf][j] = (__bf16)0.f;
#pragma unroll
    for (int cti = 0; cti < 4; ++cti) {
      int tt = tb * 16 + 2 * w + (cti >> 1);
      int u = (cti & 1) * 16 + l15;
      if (u < 25) {
#pragma unroll
        for (int kf = 0; kf < 2; ++kf)
#pragma unroll
          for (int j = 0; j < 8; ++j) {
            int cp = kf * 32 + g * 8 + j;
            xa[cti][kf][j] = xbp[(size_t)cp * kTV + tt * 25 + u];
          }
      }
    }

    f32x4 zacc[8][2];
#pragma unroll
    for (int cc = 0; cc < 8; ++cc)
#pragma unroll
      for (int vt = 0; vt < 2; ++vt) {
        f32x4 zz = {0.f, 0.f, 0.f, 0.f};
        zacc[cc][vt] = zz;
      }

    for (int s = 0; s < kS; ++s) {
      // B2 all-16 upfront (drained once at the next barrier)
      bf16x8 B2[8][2];
      const unsigned char* af = afrag + (size_t)(s * 16 + n) * 131072;
#pragma unroll
      for (int cc = 0; cc < 8; ++cc) {
        int c = w * 8 + cc;
#pragma unroll
        for (int vt = 0; vt < 2; ++vt)
          B2[cc][vt] = *(const bf16x8*)(af + ((c * 2 + vt) * 64 + l) * 16);
      }
      // stage this s's w3 frags (8KB) into LDS; barrier orders prev GEMM2/pads
      ((f32x4*)(smem + 65536))[tid] =
          ((const f32x4*)(w3f + (size_t)s * 8192))[tid];
      __syncthreads();

      // GEMM1 per o-tile from LDS w3 + xa regs; scatter immediately
      const unsigned char* w3l = smem + 65536;
#pragma unroll
      for (int ot = 0; ot < 4; ++ot) {
        bf16x8 wk0 = *(const bf16x8*)(w3l + ((ot * 2 + 0) * 64 + l) * 16);
        bf16x8 wk1 = *(const bf16x8*)(w3l + ((ot * 2 + 1) * 64 + l) * 16);
        int c = ot * 16 + l15;
#pragma unroll
        for (int cti = 0; cti < 4; ++cti) {
          f32x4 d = {0.f, 0.f, 0.f, 0.f};
          d = __builtin_amdgcn_mfma_f32_16x16x32_bf16(xa[cti][0], wk0, d, 0, 0, 0);
          d = __builtin_amdgcn_mfma_f32_16x16x32_bf16(xa[cti][1], wk1, d, 0, 0, 0);
          int tt = 2 * w + (cti >> 1);
          if (!(cti & 1)) {  // u = g*4+j
            bf16x4v pk;
            pk[0] = (__bf16)d[0]; pk[1] = (__bf16)d[1];
            pk[2] = (__bf16)d[2]; pk[3] = (__bf16)d[3];
            *(bf16x4v*)(smem + swzB16(c, tt, g * 8)) = pk;
          } else if (g < 2) {  // u = 16+g*4+j
            bf16x4v pk;
            pk[0] = (__bf16)d[0]; pk[1] = (__bf16)d[1];
            pk[2] = (__bf16)d[2]; pk[3] = (__bf16)d[3];
            *(bf16x4v*)(smem + swzB16(c, tt, 32 + g * 8)) = pk;
          } else if (g == 2) {  // u = 24 only
            *(__bf16*)(smem + swzB16(c, tt, 48)) = (__bf16)d[0];
          }
        }
      }
      // bias row u=25
      for (int i = tid; i < 1024; i += 512) {
        int c = i >> 4, t = i & 15;
        *(__bf16*)(smem + swzB16(c, t, 50)) = (__bf16)b3[s * 64 + c];
      }
      __syncthreads();
      // GEMM2: z[t][v] += X3s[c] . a_ext[c]
#pragma unroll
      for (int cc = 0; cc < 8; ++cc) {
        int c = w * 8 + cc;
        bf16x8 a2 = *(const bf16x8*)(smem + swzB16(c, l15, g * 16));
        zacc[cc][0] = __builtin_amdgcn_mfma_f32_16x16x32_bf16(a2, B2[cc][0], zacc[cc][0], 0, 0, 0);
        zacc[cc][1] = __builtin_amdgcn_mfma_f32_16x16x32_bf16(a2, B2[cc][1], zacc[cc][1], 0, 0, 0);
      }
    }
    __syncthreads();  // X3s reads done; reuse [0,51200) as zs f32 [32][400]
    float* zs = (float*)smem;
    float4* yg4 = (float4*)(y + (size_t)n * kC * kTV);
#pragma unroll
    for (int h = 0; h < 2; ++h) {
      if ((w >> 2) == h) {
        int c0l = (w & 3) * 8;
#pragma unroll
        for (int cc = 0; cc < 8; ++cc)
#pragma unroll
          for (int vt = 0; vt < 2; ++vt) {
            int v = vt * 16 + l15;
            if (v < 25) {
#pragma unroll
              for (int jj = 0; jj < 4; ++jj)
                zs[(c0l + cc) * 400 + (g * 4 + jj) * 25 + v] = zacc[cc][vt][jj];
            }
          }
      }
      __syncthreads();
      for (int i4 = tid; i4 < 3200; i4 += 512) {
        int cl = i4 / 100, r4 = i4 % 100, c = h * 32 + cl;
        bf16x4v xv = *(const bf16x4v*)(xbp + (size_t)c * kTV + tb * 400 + r4 * 4);
        f32x4 zv = *(const f32x4*)(zs + cl * 400 + r4 * 4);
        float4 o;
        o.x = fmaxf(zv[0] + (float)xv[0], 0.f);
        o.y = fmaxf(zv[1] + (float)xv[1], 0.f);
        o.z = fmaxf(zv[2] + (float)xv[2], 0.f);
        o.w = fmaxf(zv[3] + (float)xv[3], 0.f);
        yg4[c * 3200 + tb * 100 + r4] = o;
      }
      __syncthreads();
    }
  }
}

extern "C" void kernel_launch(void* const* d_in, const int* in_sizes, int n_in,
                              void* d_out, int out_size, void* d_ws, size_t ws_size,
                              hipStream_t stream) {
  const float* x = (const float*)d_in[0];
  const float* Ag = (const float*)d_in[1];
  const float* alpha = (const float*)d_in[2];
  const float* w1 = (const float*)d_in[3];
  const float* b1 = (const float*)d_in[4];
  const float* w2 = (const float*)d_in[5];
  const float* b2 = (const float*)d_in[6];
  const float* w3 = (const float*)d_in[7];
  const float* b3 = (const float*)d_in[8];
  const float* w4 = (const float*)d_in[9];
  const float* b4 = (const float*)d_in[10];
  const int* sparse = (const int*)d_in[11];

  unsigned char* ws = (unsigned char*)d_ws;
  float* y = (float*)d_out;

  hipFuncSetAttribute((const void*)k_fused,
                      hipFuncAttributeMaxDynamicSharedMemorySize, 73728);

  void* args[] = {(void*)&x,  (void*)&Ag, (void*)&alpha, (void*)&w1,
                  (void*)&b1, (void*)&w2, (void*)&b2,    (void*)&w3,
                  (void*)&b3, (void*)&w4, (void*)&b4,    (void*)&sparse,
                  (void*)&ws, (void*)&y};
  hipLaunchCooperativeKernel((const void*)k_fused, dim3(256), dim3(512), args,
                             73728, stream);
}

// Round 18
// 76.569 us; speedup vs baseline: 1.7647x; 1.7647x over previous
//
#include <hip/hip_runtime.h>
#include <cmath>

typedef __bf16 bf16x4v __attribute__((ext_vector_type(4)));
typedef __bf16 bf16x8 __attribute__((ext_vector_type(8)));
typedef float f32x4 __attribute__((ext_vector_type(4)));

namespace {
constexpr int kN = 16, kC = 64, kT = 512, kV = 25, kS = 3, kO = 64;
constexpr int kTV = kT * kV;  // 12800
// ws layout (bytes): xm f32[25600 f] | afrag[48][8192][16] | w3f[3][512][16]
constexpr size_t WS_AFRAG = 102400;
constexpr size_t WS_W3F = WS_AFRAG + (size_t)48 * 131072;  // 6,393,856
}  // namespace

// X3s: bf16 [c 64][t 16][u 32] swizzled with ((c^t)&7)<<4 (XOR bits 4-6 ONLY:
// >= 16-byte read granule). Bytes [0, 65536). w3_lds (8KB, current s) at 65536.
__device__ __forceinline__ int swzB16(int c, int t, int ubyte) {
  return (c << 10) + (((t << 6) + ubyte) ^ ((((c ^ t) & 7)) << 4));
}

// ---- k1: xm[n,c,v] = mean_t x[n,c,t,v] (phase-class accumulation, coalesced)
__global__ __launch_bounds__(256) void k1_mean(const float* __restrict__ x,
                                               float* __restrict__ xm) {
  const int bid = blockIdx.x;  // n*64 + c
  __shared__ float part[250][4];
  const int tid = threadIdx.x;
  const float4* xg4 = (const float4*)(x + (size_t)bid * kTV);
  if (tid < 250) {
    float a0 = 0.f, a1 = 0.f, a2 = 0.f, a3 = 0.f;
    for (int j = tid; j < 3200; j += 250) {  // j%250==tid -> const v-phase
      float4 v = xg4[j];
      a0 += v.x; a1 += v.y; a2 += v.z; a3 += v.w;
    }
    part[tid][0] = a0; part[tid][1] = a1; part[tid][2] = a2; part[tid][3] = a3;
  }
  __syncthreads();
  if (tid < 25) {
    float s = 0.f;
#pragma unroll
    for (int r = 0; r < 4; ++r) {
      int q = ((tid - r + 25) % 25) * 19 % 25;
#pragma unroll
      for (int p = 0; p < 10; ++p) s += part[q + 25 * p][r];
    }
    xm[bid * 25 + tid] = s * (1.f / 512.f);
  }
}

// ---- k2: a_frag (bf16, MFMA-B order, bias/colsum folded) + w3 frags
__global__ __launch_bounds__(256) void k2_attn(
    const float* __restrict__ xm, const float* __restrict__ Ag,
    const float* __restrict__ alpha, const float* __restrict__ w1,
    const float* __restrict__ b1, const float* __restrict__ w2,
    const float* __restrict__ b2, const float* __restrict__ w3,
    const float* __restrict__ w4, const float* __restrict__ b4,
    const int* __restrict__ sparse, unsigned char* __restrict__ ws) {
  const float thr = (float)sparse[0];
  const int b = blockIdx.x;
  const int s = b >> 6, n = (b >> 2) & 15, q = b & 3;
  __shared__ float xm_l[1600];
  __shared__ float x1_l[200], x2_l[200];
  __shared__ float att_l[8 * 625];
  __shared__ float attsum_l[200];
  __shared__ float ag_l[625];
  __shared__ float acs_l[25];
  __shared__ float w4_l[512];
  const int tid = threadIdx.x;
  for (int i = tid; i < 1600; i += 256) xm_l[i] = xm[n * 1600 + i];
  for (int i = tid; i < 512; i += 256) {
    float w = w4[s * 512 + i];
    w4_l[i] = (fabsf(w) > thr) ? w : 0.f;
  }
  for (int i = tid; i < 625; i += 256) ag_l[i] = Ag[s * 625 + i];
  __syncthreads();
  for (int i = tid; i < 400; i += 256) {
    int which = i / 200, idx = i % 200, r = idx / 25, u = idx % 25;
    const float* wrow = (which == 0 ? w1 : w2) + (s * 8 + r) * 64;
    float acc = 0.f;
    for (int cc = 0; cc < 64; ++cc) {
      float w = wrow[cc];
      w = (fabsf(w) > thr) ? w : 0.f;
      acc += w * xm_l[cc * 25 + u];
    }
    acc += (which == 0 ? b1 : b2)[s * 8 + r];
    if (which == 0) x1_l[idx] = acc;
    else x2_l[idx] = acc;
  }
  __syncthreads();
  for (int i = tid; i < 8 * 625; i += 256) {
    int r = i / 625, uv = i % 625, u = uv / 25, v = uv % 25;
    att_l[i] = tanhf(x1_l[r * 25 + u] - x2_l[r * 25 + v]);
  }
  __syncthreads();
  if (tid < 200) {
    int r = tid / 25, v = tid % 25;
    float sum = 0.f;
    for (int u = 0; u < 25; ++u) sum += att_l[r * 625 + u * 25 + v];
    attsum_l[tid] = sum;
  } else if (tid < 225) {
    int v = tid - 200;
    float sum = 0.f;
    for (int u = 0; u < 25; ++u) sum += ag_l[u * 25 + v];
    acs_l[v] = sum;
  }
  __syncthreads();
  const float al = alpha[0];
  // a_ext[c][u][v]: u<25 -> a ; u==25 -> colsum(a) (bias-fold) ; u>25 -> 0
  unsigned char* afrag = ws + WS_AFRAG + (size_t)(s * 16 + n) * 131072;
  for (int slot = q * 2048 + tid; slot < (q + 1) * 2048; slot += 256) {
    int c = slot >> 7, vt = (slot >> 6) & 1, l = slot & 63;
    int v = vt * 16 + (l & 15), g = l >> 4;
    bf16x8 out;
    if (v < 25) {
      float b4v = b4[s * 64 + c];
#pragma unroll
      for (int j = 0; j < 8; ++j) {
        int u = g * 8 + j;
        float val = 0.f;
        if (u < 25) {
          float acc = 0.f;
#pragma unroll
          for (int r = 0; r < 8; ++r) acc += w4_l[c * 8 + r] * att_l[r * 625 + u * 25 + v];
          val = al * (acc + b4v) + ag_l[u * 25 + v];
        } else if (u == 25) {
          float acc = 0.f;
#pragma unroll
          for (int r = 0; r < 8; ++r) acc += w4_l[c * 8 + r] * attsum_l[r * 25 + v];
          val = al * acc + 25.f * al * b4v + acs_l[v];
        }
        out[j] = (__bf16)val;
      }
    } else {
#pragma unroll
      for (int j = 0; j < 8; ++j) out[j] = (__bf16)0.f;
    }
    *(bf16x8*)(afrag + (size_t)slot * 16) = out;
  }
  // w3 frags (B-operand layout [o][c'])
  if (n == 0 && tid < 128) {
    unsigned char* w3f = ws + WS_W3F + (size_t)s * 8192;
    int slot = q * 128 + tid;
    int ot = slot >> 7, ks = (slot >> 6) & 1, l = slot & 63;
    int o = ot * 16 + (l & 15), g = l >> 4;
    bf16x8 out;
#pragma unroll
    for (int j = 0; j < 8; ++j) {
      int cp = ks * 32 + g * 8 + j;
      float w = w3[(s * 64 + o) * 64 + cp];
      out[j] = (__bf16)((fabsf(w) > thr) ? w : 0.f);
    }
    *(bf16x8*)(w3f + slot * 16) = out;
  }
}

// ---- k3: r16 structure; xa gathered from f32 x; residual from f32 x
__global__ __launch_bounds__(512) void k3_main(const float* __restrict__ x,
                                               const float* __restrict__ b3,
                                               const unsigned char* __restrict__ ws,
                                               float* __restrict__ y) {
  const int n = blockIdx.x;   // linear%8 == n%8 -> same-n blocks share XCD
  const int tb = blockIdx.y;  // 0..31 (16-t chunks)
  extern __shared__ __align__(16) unsigned char smem[];  // 73728
  const int tid = threadIdx.x;
  const int w = tid >> 6, l = tid & 63, g = l >> 4, l15 = l & 15;

  // zero X3s pad u=26..31 (3 u32 per (c,t)); visible via the s=0 barrier
  for (int idx = tid; idx < 3072; idx += 512) {
    int pair = idx / 3, k = idx % 3;
    int c = pair >> 4, t = pair & 15;
    *(unsigned int*)(smem + swzB16(c, t, 52 + 4 * k)) = 0u;
  }

  // A-frags of X gathered from f32 x: lane m=u, k=c'; t = 2w+(cti>>1). s-invariant.
  const float* xf = x + (size_t)n * kC * kTV;
  bf16x8 xa[4][2];
#pragma unroll
  for (int cti = 0; cti < 4; ++cti)
#pragma unroll
    for (int kf = 0; kf < 2; ++kf)
#pragma unroll
      for (int j = 0; j < 8; ++j) xa[cti][kf][j] = (__bf16)0.f;
#pragma unroll
  for (int cti = 0; cti < 4; ++cti) {
    int tt = tb * 16 + 2 * w + (cti >> 1);
    int u = (cti & 1) * 16 + l15;
    if (u < 25) {
#pragma unroll
      for (int kf = 0; kf < 2; ++kf)
#pragma unroll
        for (int j = 0; j < 8; ++j) {
          int cp = kf * 32 + g * 8 + j;
          xa[cti][kf][j] = (__bf16)xf[(size_t)cp * kTV + tt * 25 + u];
        }
    }
  }

  const unsigned char* afrag = ws + WS_AFRAG;
  const unsigned char* w3f = ws + WS_W3F;

  f32x4 zacc[8][2];
#pragma unroll
  for (int cc = 0; cc < 8; ++cc)
#pragma unroll
    for (int vt = 0; vt < 2; ++vt) {
      f32x4 zz = {0.f, 0.f, 0.f, 0.f};
      zacc[cc][vt] = zz;
    }

  for (int s = 0; s < kS; ++s) {
    // B2 all-16 upfront (drained once at the next barrier)
    bf16x8 B2[8][2];
    const unsigned char* af = afrag + (size_t)(s * 16 + n) * 131072;
#pragma unroll
    for (int cc = 0; cc < 8; ++cc) {
      int c = w * 8 + cc;
#pragma unroll
      for (int vt = 0; vt < 2; ++vt)
        B2[cc][vt] = *(const bf16x8*)(af + ((c * 2 + vt) * 64 + l) * 16);
    }
    // stage this s's w3 frags (8KB) into LDS; barrier also orders prev GEMM2
    ((f32x4*)(smem + 65536))[tid] =
        ((const f32x4*)(w3f + (size_t)s * 8192))[tid];
    __syncthreads();

    // GEMM1 per o-tile from LDS w3 + xa regs; scatter immediately
    const unsigned char* w3l = smem + 65536;
#pragma unroll
    for (int ot = 0; ot < 4; ++ot) {
      bf16x8 wk0 = *(const bf16x8*)(w3l + ((ot * 2 + 0) * 64 + l) * 16);
      bf16x8 wk1 = *(const bf16x8*)(w3l + ((ot * 2 + 1) * 64 + l) * 16);
      int c = ot * 16 + l15;
#pragma unroll
      for (int cti = 0; cti < 4; ++cti) {
        f32x4 d = {0.f, 0.f, 0.f, 0.f};
        d = __builtin_amdgcn_mfma_f32_16x16x32_bf16(xa[cti][0], wk0, d, 0, 0, 0);
        d = __builtin_amdgcn_mfma_f32_16x16x32_bf16(xa[cti][1], wk1, d, 0, 0, 0);
        int tt = 2 * w + (cti >> 1);
        if (!(cti & 1)) {  // u = g*4+j
          bf16x4v pk;
          pk[0] = (__bf16)d[0]; pk[1] = (__bf16)d[1];
          pk[2] = (__bf16)d[2]; pk[3] = (__bf16)d[3];
          *(bf16x4v*)(smem + swzB16(c, tt, g * 8)) = pk;
        } else if (g < 2) {  // u = 16+g*4+j
          bf16x4v pk;
          pk[0] = (__bf16)d[0]; pk[1] = (__bf16)d[1];
          pk[2] = (__bf16)d[2]; pk[3] = (__bf16)d[3];
          *(bf16x4v*)(smem + swzB16(c, tt, 32 + g * 8)) = pk;
        } else if (g == 2) {  // u = 24 only
          *(__bf16*)(smem + swzB16(c, tt, 48)) = (__bf16)d[0];
        }
      }
    }
    // bias row u=25
    for (int i = tid; i < 1024; i += 512) {
      int c = i >> 4, t = i & 15;
      *(__bf16*)(smem + swzB16(c, t, 50)) = (__bf16)b3[s * 64 + c];
    }
    __syncthreads();
    // GEMM2: z[t][v] += X3s[c] . a_ext[c]  (per-c batched; M=16 = all t)
#pragma unroll
    for (int cc = 0; cc < 8; ++cc) {
      int c = w * 8 + cc;
      bf16x8 a2 = *(const bf16x8*)(smem + swzB16(c, l15, g * 16));
      zacc[cc][0] = __builtin_amdgcn_mfma_f32_16x16x32_bf16(a2, B2[cc][0], zacc[cc][0], 0, 0, 0);
      zacc[cc][1] = __builtin_amdgcn_mfma_f32_16x16x32_bf16(a2, B2[cc][1], zacc[cc][1], 0, 0, 0);
    }
  }
  __syncthreads();  // all X3s reads done; reuse [0,51200) as zs f32 [32][400]
  float* zs = (float*)smem;
  const float4* xg4 = (const float4*)(x + (size_t)n * kC * kTV);
  float4* yg4 = (float4*)(y + (size_t)n * kC * kTV);
#pragma unroll
  for (int h = 0; h < 2; ++h) {
    if ((w >> 2) == h) {
      int c0l = (w & 3) * 8;
#pragma unroll
      for (int cc = 0; cc < 8; ++cc)
#pragma unroll
        for (int vt = 0; vt < 2; ++vt) {
          int v = vt * 16 + l15;
          if (v < 25) {
#pragma unroll
            for (int jj = 0; jj < 4; ++jj)
              zs[(c0l + cc) * 400 + (g * 4 + jj) * 25 + v] = zacc[cc][vt][jj];
          }
        }
    }
    __syncthreads();
    for (int i4 = tid; i4 < 3200; i4 += 512) {
      int cl = i4 / 100, r4 = i4 % 100, c = h * 32 + cl;
      float4 xv = xg4[c * 3200 + tb * 100 + r4];
      f32x4 zv = *(const f32x4*)(zs + cl * 400 + r4 * 4);
      float4 o;
      o.x = fmaxf(zv[0] + xv.x, 0.f);
      o.y = fmaxf(zv[1] + xv.y, 0.f);
      o.z = fmaxf(zv[2] + xv.z, 0.f);
      o.w = fmaxf(zv[3] + xv.w, 0.f);
      yg4[c * 3200 + tb * 100 + r4] = o;
    }
    __syncthreads();
  }
}

extern "C" void kernel_launch(void* const* d_in, const int* in_sizes, int n_in,
                              void* d_out, int out_size, void* d_ws, size_t ws_size,
                              hipStream_t stream) {
  const float* x = (const float*)d_in[0];
  const float* Ag = (const float*)d_in[1];
  const float* alpha = (const float*)d_in[2];
  const float* w1 = (const float*)d_in[3];
  const float* b1 = (const float*)d_in[4];
  const float* w2 = (const float*)d_in[5];
  const float* b2 = (const float*)d_in[6];
  const float* w3 = (const float*)d_in[7];
  const float* b3 = (const float*)d_in[8];
  const float* w4 = (const float*)d_in[9];
  const float* b4 = (const float*)d_in[10];
  const int* sparse = (const int*)d_in[11];

  unsigned char* ws = (unsigned char*)d_ws;
  float* xm = (float*)ws;  // [16][64][25] f32 at offset 0
  float* y = (float*)d_out;

  hipFuncSetAttribute((const void*)k3_main,
                      hipFuncAttributeMaxDynamicSharedMemorySize, 73728);

  k1_mean<<<kN * kC, 256, 0, stream>>>(x, xm);
  k2_attn<<<kS * kN * 4, 256, 0, stream>>>(xm, Ag, alpha, w1, b1, w2, b2, w3, w4,
                                           b4, sparse, ws);
  dim3 g3(kN, kT / 16);
  k3_main<<<g3, 512, 73728, stream>>>(x, b3, ws, y);
}

// Round 19
// 74.644 us; speedup vs baseline: 1.8103x; 1.0258x over previous
//
#include <hip/hip_runtime.h>
#include <cmath>

typedef __bf16 bf16x4v __attribute__((ext_vector_type(4)));
typedef __bf16 bf16x8 __attribute__((ext_vector_type(8)));
typedef float f32x4 __attribute__((ext_vector_type(4)));

namespace {
constexpr int kN = 16, kC = 64, kT = 512, kV = 25, kS = 3, kO = 64;
constexpr int kTV = kT * kV;  // 12800
// ws layout (bytes): xm f32[25600 f] | afrag[48][8192][16] | w3f[3][512][16] | x_bf bf16
constexpr size_t WS_AFRAG = 102400;
constexpr size_t WS_W3F = WS_AFRAG + (size_t)48 * 131072;  // 6,393,856
constexpr size_t WS_XBF = WS_W3F + 3 * 8192;               // 6,418,432
}  // namespace

// X3s: bf16 [c 64][t 16][u 32] swizzled with ((c^t)&7)<<4 (XOR bits 4-6 ONLY:
// >= 16-byte read granule). Bytes [0, 65536). w3_lds (8KB, current s) at 65536.
__device__ __forceinline__ int swzB16(int c, int t, int ubyte) {
  return (c << 10) + (((t << 6) + ubyte) ^ ((((c ^ t) & 7)) << 4));
}

// ---- k1: stream x f32 -> x_bf bf16 (natural layout) + mean via phase classes
__global__ __launch_bounds__(256) void k1_cvt(const float* __restrict__ x,
                                              __bf16* __restrict__ xbf,
                                              float* __restrict__ xm) {
  const int bid = blockIdx.x;  // n*64 + c
  __shared__ float part[250][4];
  const int tid = threadIdx.x;
  const float4* xg4 = (const float4*)(x + (size_t)bid * kTV);
  bf16x4v* xb4 = (bf16x4v*)(xbf + (size_t)bid * kTV);
  if (tid < 250) {
    float a0 = 0.f, a1 = 0.f, a2 = 0.f, a3 = 0.f;
    for (int j = tid; j < 3200; j += 250) {  // j%250==tid -> const v-phase
      float4 v = xg4[j];
      a0 += v.x; a1 += v.y; a2 += v.z; a3 += v.w;
      bf16x4v o;
      o[0] = (__bf16)v.x; o[1] = (__bf16)v.y;
      o[2] = (__bf16)v.z; o[3] = (__bf16)v.w;
      xb4[j] = o;
    }
    part[tid][0] = a0; part[tid][1] = a1; part[tid][2] = a2; part[tid][3] = a3;
  }
  __syncthreads();
  if (tid < 25) {
    float s = 0.f;
#pragma unroll
    for (int r = 0; r < 4; ++r) {
      int q = ((tid - r + 25) % 25) * 19 % 25;
#pragma unroll
      for (int p = 0; p < 10; ++p) s += part[q + 25 * p][r];
    }
    xm[bid * 25 + tid] = s * (1.f / 512.f);
  }
}

// ---- k2: a_frag (bf16, MFMA-B order, bias/colsum folded) + w3 frags
__global__ __launch_bounds__(256) void k2_attn(
    const float* __restrict__ xm, const float* __restrict__ Ag,
    const float* __restrict__ alpha, const float* __restrict__ w1,
    const float* __restrict__ b1, const float* __restrict__ w2,
    const float* __restrict__ b2, const float* __restrict__ w3,
    const float* __restrict__ w4, const float* __restrict__ b4,
    const int* __restrict__ sparse, unsigned char* __restrict__ ws) {
  const float thr = (float)sparse[0];
  const int b = blockIdx.x;
  const int s = b >> 6, n = (b >> 2) & 15, q = b & 3;
  __shared__ float xm_l[1600];
  __shared__ float x1_l[200], x2_l[200];
  __shared__ float att_l[8 * 625];
  __shared__ float attsum_l[200];
  __shared__ float ag_l[625];
  __shared__ float acs_l[25];
  __shared__ float w4_l[512];
  const int tid = threadIdx.x;
  for (int i = tid; i < 1600; i += 256) xm_l[i] = xm[n * 1600 + i];
  for (int i = tid; i < 512; i += 256) {
    float w = w4[s * 512 + i];
    w4_l[i] = (fabsf(w) > thr) ? w : 0.f;
  }
  for (int i = tid; i < 625; i += 256) ag_l[i] = Ag[s * 625 + i];
  __syncthreads();
  for (int i = tid; i < 400; i += 256) {
    int which = i / 200, idx = i % 200, r = idx / 25, u = idx % 25;
    const float* wrow = (which == 0 ? w1 : w2) + (s * 8 + r) * 64;
    float acc = 0.f;
    for (int cc = 0; cc < 64; ++cc) {
      float w = wrow[cc];
      w = (fabsf(w) > thr) ? w : 0.f;
      acc += w * xm_l[cc * 25 + u];
    }
    acc += (which == 0 ? b1 : b2)[s * 8 + r];
    if (which == 0) x1_l[idx] = acc;
    else x2_l[idx] = acc;
  }
  __syncthreads();
  for (int i = tid; i < 8 * 625; i += 256) {
    int r = i / 625, uv = i % 625, u = uv / 25, v = uv % 25;
    att_l[i] = tanhf(x1_l[r * 25 + u] - x2_l[r * 25 + v]);
  }
  __syncthreads();
  if (tid < 200) {
    int r = tid / 25, v = tid % 25;
    float sum = 0.f;
    for (int u = 0; u < 25; ++u) sum += att_l[r * 625 + u * 25 + v];
    attsum_l[tid] = sum;
  } else if (tid < 225) {
    int v = tid - 200;
    float sum = 0.f;
    for (int u = 0; u < 25; ++u) sum += ag_l[u * 25 + v];
    acs_l[v] = sum;
  }
  __syncthreads();
  const float al = alpha[0];
  // a_ext[c][u][v]: u<25 -> a ; u==25 -> colsum(a) (bias-fold) ; u>25 -> 0
  unsigned char* afrag = ws + WS_AFRAG + (size_t)(s * 16 + n) * 131072;
  for (int slot = q * 2048 + tid; slot < (q + 1) * 2048; slot += 256) {
    int c = slot >> 7, vt = (slot >> 6) & 1, l = slot & 63;
    int v = vt * 16 + (l & 15), g = l >> 4;
    bf16x8 out;
    if (v < 25) {
      float b4v = b4[s * 64 + c];
#pragma unroll
      for (int j = 0; j < 8; ++j) {
        int u = g * 8 + j;
        float val = 0.f;
        if (u < 25) {
          float acc = 0.f;
#pragma unroll
          for (int r = 0; r < 8; ++r) acc += w4_l[c * 8 + r] * att_l[r * 625 + u * 25 + v];
          val = al * (acc + b4v) + ag_l[u * 25 + v];
        } else if (u == 25) {
          float acc = 0.f;
#pragma unroll
          for (int r = 0; r < 8; ++r) acc += w4_l[c * 8 + r] * attsum_l[r * 25 + v];
          val = al * acc + 25.f * al * b4v + acs_l[v];
        }
        out[j] = (__bf16)val;
      }
    } else {
#pragma unroll
      for (int j = 0; j < 8; ++j) out[j] = (__bf16)0.f;
    }
    *(bf16x8*)(afrag + (size_t)slot * 16) = out;
  }
  // w3 frags (B-operand layout [o][c'])
  if (n == 0 && tid < 128) {
    unsigned char* w3f = ws + WS_W3F + (size_t)s * 8192;
    int slot = q * 128 + tid;
    int ot = slot >> 7, ks = (slot >> 6) & 1, l = slot & 63;
    int o = ot * 16 + (l & 15), g = l >> 4;
    bf16x8 out;
#pragma unroll
    for (int j = 0; j < 8; ++j) {
      int cp = ks * 32 + g * 8 + j;
      float w = w3[(s * 64 + o) * 64 + cp];
      out[j] = (__bf16)((fabsf(w) > thr) ? w : 0.f);
    }
    *(bf16x8*)(w3f + slot * 16) = out;
  }
}

// ---- k3: TT=16; xa regs from x_bf; w3-per-s in LDS; B2 all-16; LDS 72KB
__global__ __launch_bounds__(512) void k3_main(const __bf16* __restrict__ xbf,
                                               const float* __restrict__ b3,
                                               const unsigned char* __restrict__ ws,
                                               float* __restrict__ y) {
  const int n = blockIdx.x;   // linear%8 == n%8 -> same-n blocks share XCD
  const int tb = blockIdx.y;  // 0..31 (16-t chunks)
  extern __shared__ __align__(16) unsigned char smem[];  // 73728
  const int tid = threadIdx.x;
  const int w = tid >> 6, l = tid & 63, g = l >> 4, l15 = l & 15;

  // zero X3s pad u=26..31 (3 u32 per (c,t)); visible via the s=0 barrier
  for (int idx = tid; idx < 3072; idx += 512) {
    int pair = idx / 3, k = idx % 3;
    int c = pair >> 4, t = pair & 15;
    *(unsigned int*)(smem + swzB16(c, t, 52 + 4 * k)) = 0u;
  }

  // A-frags of X from x_bf: lane m=u, k=c'; t = 2w+(cti>>1). s-invariant.
  bf16x8 xa[4][2];
#pragma unroll
  for (int cti = 0; cti < 4; ++cti)
#pragma unroll
    for (int kf = 0; kf < 2; ++kf)
#pragma unroll
      for (int j = 0; j < 8; ++j) xa[cti][kf][j] = (__bf16)0.f;
  {
    const __bf16* xbp = xbf + (size_t)n * kC * kTV;
#pragma unroll
    for (int cti = 0; cti < 4; ++cti) {
      int tt = tb * 16 + 2 * w + (cti >> 1);
      int u = (cti & 1) * 16 + l15;
      if (u < 25) {
#pragma unroll
        for (int kf = 0; kf < 2; ++kf)
#pragma unroll
          for (int j = 0; j < 8; ++j) {
            int cp = kf * 32 + g * 8 + j;
            xa[cti][kf][j] = xbp[(size_t)cp * kTV + tt * 25 + u];
          }
      }
    }
  }

  const unsigned char* afrag = ws + WS_AFRAG;
  const unsigned char* w3f = ws + WS_W3F;

  f32x4 zacc[8][2];
#pragma unroll
  for (int cc = 0; cc < 8; ++cc)
#pragma unroll
    for (int vt = 0; vt < 2; ++vt) {
      f32x4 zz = {0.f, 0.f, 0.f, 0.f};
      zacc[cc][vt] = zz;
    }

  for (int s = 0; s < kS; ++s) {
    // B2 all-16 upfront (drained once at the next barrier)
    bf16x8 B2[8][2];
    const unsigned char* af = afrag + (size_t)(s * 16 + n) * 131072;
#pragma unroll
    for (int cc = 0; cc < 8; ++cc) {
      int c = w * 8 + cc;
#pragma unroll
      for (int vt = 0; vt < 2; ++vt)
        B2[cc][vt] = *(const bf16x8*)(af + ((c * 2 + vt) * 64 + l) * 16);
    }
    // stage this s's w3 frags (8KB) into LDS; barrier also orders prev GEMM2
    ((f32x4*)(smem + 65536))[tid] =
        ((const f32x4*)(w3f + (size_t)s * 8192))[tid];
    __syncthreads();

    // GEMM1 per o-tile from LDS w3 + xa regs; scatter immediately
    const unsigned char* w3l = smem + 65536;
#pragma unroll
    for (int ot = 0; ot < 4; ++ot) {
      bf16x8 wk0 = *(const bf16x8*)(w3l + ((ot * 2 + 0) * 64 + l) * 16);
      bf16x8 wk1 = *(const bf16x8*)(w3l + ((ot * 2 + 1) * 64 + l) * 16);
      int c = ot * 16 + l15;
#pragma unroll
      for (int cti = 0; cti < 4; ++cti) {
        f32x4 d = {0.f, 0.f, 0.f, 0.f};
        d = __builtin_amdgcn_mfma_f32_16x16x32_bf16(xa[cti][0], wk0, d, 0, 0, 0);
        d = __builtin_amdgcn_mfma_f32_16x16x32_bf16(xa[cti][1], wk1, d, 0, 0, 0);
        int tt = 2 * w + (cti >> 1);
        if (!(cti & 1)) {  // u = g*4+j
          bf16x4v pk;
          pk[0] = (__bf16)d[0]; pk[1] = (__bf16)d[1];
          pk[2] = (__bf16)d[2]; pk[3] = (__bf16)d[3];
          *(bf16x4v*)(smem + swzB16(c, tt, g * 8)) = pk;
        } else if (g < 2) {  // u = 16+g*4+j
          bf16x4v pk;
          pk[0] = (__bf16)d[0]; pk[1] = (__bf16)d[1];
          pk[2] = (__bf16)d[2]; pk[3] = (__bf16)d[3];
          *(bf16x4v*)(smem + swzB16(c, tt, 32 + g * 8)) = pk;
        } else if (g == 2) {  // u = 24 only
          *(__bf16*)(smem + swzB16(c, tt, 48)) = (__bf16)d[0];
        }
      }
    }
    // bias row u=25
    for (int i = tid; i < 1024; i += 512) {
      int c = i >> 4, t = i & 15;
      *(__bf16*)(smem + swzB16(c, t, 50)) = (__bf16)b3[s * 64 + c];
    }
    __syncthreads();
    // GEMM2: z[t][v] += X3s[c] . a_ext[c]  (per-c batched; M=16 = all t)
#pragma unroll
    for (int cc = 0; cc < 8; ++cc) {
      int c = w * 8 + cc;
      bf16x8 a2 = *(const bf16x8*)(smem + swzB16(c, l15, g * 16));
      zacc[cc][0] = __builtin_amdgcn_mfma_f32_16x16x32_bf16(a2, B2[cc][0], zacc[cc][0], 0, 0, 0);
      zacc[cc][1] = __builtin_amdgcn_mfma_f32_16x16x32_bf16(a2, B2[cc][1], zacc[cc][1], 0, 0, 0);
    }
  }
  __syncthreads();  // all X3s reads done; reuse [0,51200) as zs f32 [32][400]
  float* zs = (float*)smem;
  const __bf16* xbp = xbf + (size_t)n * kC * kTV;
  float4* yg4 = (float4*)(y + (size_t)n * kC * kTV);
#pragma unroll
  for (int h = 0; h < 2; ++h) {
    if ((w >> 2) == h) {
      int c0l = (w & 3) * 8;
#pragma unroll
      for (int cc = 0; cc < 8; ++cc)
#pragma unroll
        for (int vt = 0; vt < 2; ++vt) {
          int v = vt * 16 + l15;
          if (v < 25) {
#pragma unroll
            for (int jj = 0; jj < 4; ++jj)
              zs[(c0l + cc) * 400 + (g * 4 + jj) * 25 + v] = zacc[cc][vt][jj];
          }
        }
    }
    __syncthreads();
    for (int i4 = tid; i4 < 3200; i4 += 512) {
      int cl = i4 / 100, r4 = i4 % 100, c = h * 32 + cl;
      bf16x4v xv = *(const bf16x4v*)(xbp + (size_t)c * kTV + tb * 400 + r4 * 4);
      f32x4 zv = *(const f32x4*)(zs + cl * 400 + r4 * 4);
      float4 o;
      o.x = fmaxf(zv[0] + (float)xv[0], 0.f);
      o.y = fmaxf(zv[1] + (float)xv[1], 0.f);
      o.z = fmaxf(zv[2] + (float)xv[2], 0.f);
      o.w = fmaxf(zv[3] + (float)xv[3], 0.f);
      yg4[c * 3200 + tb * 100 + r4] = o;
    }
    __syncthreads();
  }
}

extern "C" void kernel_launch(void* const* d_in, const int* in_sizes, int n_in,
                              void* d_out, int out_size, void* d_ws, size_t ws_size,
                              hipStream_t stream) {
  const float* x = (const float*)d_in[0];
  const float* Ag = (const float*)d_in[1];
  const float* alpha = (const float*)d_in[2];
  const float* w1 = (const float*)d_in[3];
  const float* b1 = (const float*)d_in[4];
  const float* w2 = (const float*)d_in[5];
  const float* b2 = (const float*)d_in[6];
  const float* w3 = (const float*)d_in[7];
  const float* b3 = (const float*)d_in[8];
  const float* w4 = (const float*)d_in[9];
  const float* b4 = (const float*)d_in[10];
  const int* sparse = (const int*)d_in[11];

  unsigned char* ws = (unsigned char*)d_ws;
  float* xm = (float*)ws;  // [16][64][25] f32 at offset 0
  __bf16* xbf = (__bf16*)(ws + WS_XBF);
  float* y = (float*)d_out;

  hipFuncSetAttribute((const void*)k3_main,
                      hipFuncAttributeMaxDynamicSharedMemorySize, 73728);

  k1_cvt<<<kN * kC, 256, 0, stream>>>(x, xbf, xm);
  k2_attn<<<kS * kN * 4, 256, 0, stream>>>(xm, Ag, alpha, w1, b1, w2, b2, w3, w4,
                                           b4, sparse, ws);
  dim3 g3(kN, kT / 16);
  k3_main<<<g3, 512, 73728, stream>>>(xbf, b3, ws, y);
}

// Round 20
// 73.931 us; speedup vs baseline: 1.8277x; 1.0096x over previous
//
#include <hip/hip_runtime.h>
#include <cmath>

typedef __bf16 bf16x4v __attribute__((ext_vector_type(4)));
typedef __bf16 bf16x8 __attribute__((ext_vector_type(8)));
typedef float f32x4 __attribute__((ext_vector_type(4)));

namespace {
constexpr int kN = 16, kC = 64, kT = 512, kV = 25, kS = 3, kO = 64;
constexpr int kTV = kT * kV;  // 12800
// ws layout (bytes): xm f32[25600 f] | afrag[48][8192][16] | w3f[3][512][16] | x_bf bf16
constexpr size_t WS_AFRAG = 102400;
constexpr size_t WS_W3F = WS_AFRAG + (size_t)48 * 131072;  // 6,393,856
constexpr size_t WS_XBF = WS_W3F + 3 * 8192;               // 6,418,432
}  // namespace

// lgkmcnt-only barrier (T4): LDS writes visible across the barrier, but
// outstanding GLOBAL loads (vmcnt) stay in flight -- unlike __syncthreads(),
// which drains vmcnt(0) too. Memory-clobber asm on both sides fences compiler
// reordering of memory ops across the barrier.
__device__ __forceinline__ void lgkm_barrier() {
  asm volatile("s_waitcnt lgkmcnt(0)" ::: "memory");
  __builtin_amdgcn_s_barrier();
  asm volatile("" ::: "memory");
}

// X3s: bf16 [c 64][t 16][u 32] swizzled with ((c^t)&7)<<4 (XOR bits 4-6 ONLY:
// >= 16-byte read granule). Bytes [0, 65536). w3_lds (8KB, current s) at 65536.
__device__ __forceinline__ int swzB16(int c, int t, int ubyte) {
  return (c << 10) + (((t << 6) + ubyte) ^ ((((c ^ t) & 7)) << 4));
}

// ---- k1: stream x f32 -> x_bf bf16 (natural layout) + mean via phase classes
__global__ __launch_bounds__(256) void k1_cvt(const float* __restrict__ x,
                                              __bf16* __restrict__ xbf,
                                              float* __restrict__ xm) {
  const int bid = blockIdx.x;  // n*64 + c
  __shared__ float part[250][4];
  const int tid = threadIdx.x;
  const float4* xg4 = (const float4*)(x + (size_t)bid * kTV);
  bf16x4v* xb4 = (bf16x4v*)(xbf + (size_t)bid * kTV);
  if (tid < 250) {
    float a0 = 0.f, a1 = 0.f, a2 = 0.f, a3 = 0.f;
    for (int j = tid; j < 3200; j += 250) {  // j%250==tid -> const v-phase
      float4 v = xg4[j];
      a0 += v.x; a1 += v.y; a2 += v.z; a3 += v.w;
      bf16x4v o;
      o[0] = (__bf16)v.x; o[1] = (__bf16)v.y;
      o[2] = (__bf16)v.z; o[3] = (__bf16)v.w;
      xb4[j] = o;
    }
    part[tid][0] = a0; part[tid][1] = a1; part[tid][2] = a2; part[tid][3] = a3;
  }
  __syncthreads();
  if (tid < 25) {
    float s = 0.f;
#pragma unroll
    for (int r = 0; r < 4; ++r) {
      int q = ((tid - r + 25) % 25) * 19 % 25;
#pragma unroll
      for (int p = 0; p < 10; ++p) s += part[q + 25 * p][r];
    }
    xm[bid * 25 + tid] = s * (1.f / 512.f);
  }
}

// ---- k2: a_frag (bf16, MFMA-B order, bias/colsum folded) + w3 frags
__global__ __launch_bounds__(256) void k2_attn(
    const float* __restrict__ xm, const float* __restrict__ Ag,
    const float* __restrict__ alpha, const float* __restrict__ w1,
    const float* __restrict__ b1, const float* __restrict__ w2,
    const float* __restrict__ b2, const float* __restrict__ w3,
    const float* __restrict__ w4, const float* __restrict__ b4,
    const int* __restrict__ sparse, unsigned char* __restrict__ ws) {
  const float thr = (float)sparse[0];
  const int b = blockIdx.x;
  const int s = b >> 6, n = (b >> 2) & 15, q = b & 3;
  __shared__ float xm_l[1600];
  __shared__ float x1_l[200], x2_l[200];
  __shared__ float att_l[8 * 625];
  __shared__ float attsum_l[200];
  __shared__ float ag_l[625];
  __shared__ float acs_l[25];
  __shared__ float w4_l[512];
  const int tid = threadIdx.x;
  for (int i = tid; i < 1600; i += 256) xm_l[i] = xm[n * 1600 + i];
  for (int i = tid; i < 512; i += 256) {
    float w = w4[s * 512 + i];
    w4_l[i] = (fabsf(w) > thr) ? w : 0.f;
  }
  for (int i = tid; i < 625; i += 256) ag_l[i] = Ag[s * 625 + i];
  __syncthreads();
  for (int i = tid; i < 400; i += 256) {
    int which = i / 200, idx = i % 200, r = idx / 25, u = idx % 25;
    const float* wrow = (which == 0 ? w1 : w2) + (s * 8 + r) * 64;
    float acc = 0.f;
    for (int cc = 0; cc < 64; ++cc) {
      float w = wrow[cc];
      w = (fabsf(w) > thr) ? w : 0.f;
      acc += w * xm_l[cc * 25 + u];
    }
    acc += (which == 0 ? b1 : b2)[s * 8 + r];
    if (which == 0) x1_l[idx] = acc;
    else x2_l[idx] = acc;
  }
  __syncthreads();
  for (int i = tid; i < 8 * 625; i += 256) {
    int r = i / 625, uv = i % 625, u = uv / 25, v = uv % 25;
    att_l[i] = tanhf(x1_l[r * 25 + u] - x2_l[r * 25 + v]);
  }
  __syncthreads();
  if (tid < 200) {
    int r = tid / 25, v = tid % 25;
    float sum = 0.f;
    for (int u = 0; u < 25; ++u) sum += att_l[r * 625 + u * 25 + v];
    attsum_l[tid] = sum;
  } else if (tid < 225) {
    int v = tid - 200;
    float sum = 0.f;
    for (int u = 0; u < 25; ++u) sum += ag_l[u * 25 + v];
    acs_l[v] = sum;
  }
  __syncthreads();
  const float al = alpha[0];
  // a_ext[c][u][v]: u<25 -> a ; u==25 -> colsum(a) (bias-fold) ; u>25 -> 0
  unsigned char* afrag = ws + WS_AFRAG + (size_t)(s * 16 + n) * 131072;
  for (int slot = q * 2048 + tid; slot < (q + 1) * 2048; slot += 256) {
    int c = slot >> 7, vt = (slot >> 6) & 1, l = slot & 63;
    int v = vt * 16 + (l & 15), g = l >> 4;
    bf16x8 out;
    if (v < 25) {
      float b4v = b4[s * 64 + c];
#pragma unroll
      for (int j = 0; j < 8; ++j) {
        int u = g * 8 + j;
        float val = 0.f;
        if (u < 25) {
          float acc = 0.f;
#pragma unroll
          for (int r = 0; r < 8; ++r) acc += w4_l[c * 8 + r] * att_l[r * 625 + u * 25 + v];
          val = al * (acc + b4v) + ag_l[u * 25 + v];
        } else if (u == 25) {
          float acc = 0.f;
#pragma unroll
          for (int r = 0; r < 8; ++r) acc += w4_l[c * 8 + r] * attsum_l[r * 25 + v];
          val = al * acc + 25.f * al * b4v + acs_l[v];
        }
        out[j] = (__bf16)val;
      }
    } else {
#pragma unroll
      for (int j = 0; j < 8; ++j) out[j] = (__bf16)0.f;
    }
    *(bf16x8*)(afrag + (size_t)slot * 16) = out;
  }
  // w3 frags (B-operand layout [o][c'])
  if (n == 0 && tid < 128) {
    unsigned char* w3f = ws + WS_W3F + (size_t)s * 8192;
    int slot = q * 128 + tid;
    int ot = slot >> 7, ks = (slot >> 6) & 1, l = slot & 63;
    int o = ot * 16 + (l & 15), g = l >> 4;
    bf16x8 out;
#pragma unroll
    for (int j = 0; j < 8; ++j) {
      int cp = ks * 32 + g * 8 + j;
      float w = w3[(s * 64 + o) * 64 + cp];
      out[j] = (__bf16)((fabsf(w) > thr) ? w : 0.f);
    }
    *(bf16x8*)(w3f + slot * 16) = out;
  }
}

// ---- k3: r16 structure + lgkm-only barriers (T4) + w3 stage pipeline
__global__ __launch_bounds__(512) void k3_main(const __bf16* __restrict__ xbf,
                                               const float* __restrict__ b3,
                                               const unsigned char* __restrict__ ws,
                                               float* __restrict__ y) {
  const int n = blockIdx.x;   // linear%8 == n%8 -> same-n blocks share XCD
  const int tb = blockIdx.y;  // 0..31 (16-t chunks)
  extern __shared__ __align__(16) unsigned char smem[];  // 73728
  const int tid = threadIdx.x;
  const int w = tid >> 6, l = tid & 63, g = l >> 4, l15 = l & 15;

  // zero X3s pad u=26..31 (3 u32 per (c,t)); visible via the s=0 barrier
  for (int idx = tid; idx < 3072; idx += 512) {
    int pair = idx / 3, k = idx % 3;
    int c = pair >> 4, t = pair & 15;
    *(unsigned int*)(smem + swzB16(c, t, 52 + 4 * k)) = 0u;
  }

  // A-frags of X from x_bf: lane m=u, k=c'; t = 2w+(cti>>1). s-invariant.
  bf16x8 xa[4][2];
#pragma unroll
  for (int cti = 0; cti < 4; ++cti)
#pragma unroll
    for (int kf = 0; kf < 2; ++kf)
#pragma unroll
      for (int j = 0; j < 8; ++j) xa[cti][kf][j] = (__bf16)0.f;
  {
    const __bf16* xbp = xbf + (size_t)n * kC * kTV;
#pragma unroll
    for (int cti = 0; cti < 4; ++cti) {
      int tt = tb * 16 + 2 * w + (cti >> 1);
      int u = (cti & 1) * 16 + l15;
      if (u < 25) {
#pragma unroll
        for (int kf = 0; kf < 2; ++kf)
#pragma unroll
          for (int j = 0; j < 8; ++j) {
            int cp = kf * 32 + g * 8 + j;
            xa[cti][kf][j] = xbp[(size_t)cp * kTV + tt * 25 + u];
          }
      }
    }
  }

  const unsigned char* afrag = ws + WS_AFRAG;
  const unsigned char* w3f = ws + WS_W3F;

  f32x4 zacc[8][2];
#pragma unroll
  for (int cc = 0; cc < 8; ++cc)
#pragma unroll
    for (int vt = 0; vt < 2; ++vt) {
      f32x4 zz = {0.f, 0.f, 0.f, 0.f};
      zacc[cc][vt] = zz;
    }

  // w3-stage pipeline: hold s's 16B in regs, prefetch s+1 during s's compute
  f32x4 wstage = ((const f32x4*)w3f)[tid];  // s = 0

  for (int s = 0; s < kS; ++s) {
    // B2 all-16: issued here, stay IN FLIGHT across the lgkm-only barrier;
    // their vmcnt wait lands at first GEMM2 use (register dependency).
    bf16x8 B2[8][2];
    const unsigned char* af = afrag + (size_t)(s * 16 + n) * 131072;
#pragma unroll
    for (int cc = 0; cc < 8; ++cc) {
      int c = w * 8 + cc;
#pragma unroll
      for (int vt = 0; vt < 2; ++vt)
        B2[cc][vt] = *(const bf16x8*)(af + ((c * 2 + vt) * 64 + l) * 16);
    }
    // ds_write this s's w3 frags (held in regs); prefetch next s's
    ((f32x4*)(smem + 65536))[tid] = wstage;
    if (s < kS - 1) wstage = ((const f32x4*)(w3f + (size_t)(s + 1) * 8192))[tid];
    lgkm_barrier();  // w3l + pads/scatter(s-1)-reads ordered; B2 NOT drained

    // GEMM1 per o-tile from LDS w3 + xa regs; scatter immediately
    const unsigned char* w3l = smem + 65536;
#pragma unroll
    for (int ot = 0; ot < 4; ++ot) {
      bf16x8 wk0 = *(const bf16x8*)(w3l + ((ot * 2 + 0) * 64 + l) * 16);
      bf16x8 wk1 = *(const bf16x8*)(w3l + ((ot * 2 + 1) * 64 + l) * 16);
      int c = ot * 16 + l15;
#pragma unroll
      for (int cti = 0; cti < 4; ++cti) {
        f32x4 d = {0.f, 0.f, 0.f, 0.f};
        d = __builtin_amdgcn_mfma_f32_16x16x32_bf16(xa[cti][0], wk0, d, 0, 0, 0);
        d = __builtin_amdgcn_mfma_f32_16x16x32_bf16(xa[cti][1], wk1, d, 0, 0, 0);
        int tt = 2 * w + (cti >> 1);
        if (!(cti & 1)) {  // u = g*4+j
          bf16x4v pk;
          pk[0] = (__bf16)d[0]; pk[1] = (__bf16)d[1];
          pk[2] = (__bf16)d[2]; pk[3] = (__bf16)d[3];
          *(bf16x4v*)(smem + swzB16(c, tt, g * 8)) = pk;
        } else if (g < 2) {  // u = 16+g*4+j
          bf16x4v pk;
          pk[0] = (__bf16)d[0]; pk[1] = (__bf16)d[1];
          pk[2] = (__bf16)d[2]; pk[3] = (__bf16)d[3];
          *(bf16x4v*)(smem + swzB16(c, tt, 32 + g * 8)) = pk;
        } else if (g == 2) {  // u = 24 only
          *(__bf16*)(smem + swzB16(c, tt, 48)) = (__bf16)d[0];
        }
      }
    }
    // bias row u=25
    for (int i = tid; i < 1024; i += 512) {
      int c = i >> 4, t = i & 15;
      *(__bf16*)(smem + swzB16(c, t, 50)) = (__bf16)b3[s * 64 + c];
    }
    lgkm_barrier();  // X3s scatter visible
    // GEMM2: z[t][v] += X3s[c] . a_ext[c]  (per-c batched; M=16 = all t)
#pragma unroll
    for (int cc = 0; cc < 8; ++cc) {
      int c = w * 8 + cc;
      bf16x8 a2 = *(const bf16x8*)(smem + swzB16(c, l15, g * 16));
      zacc[cc][0] = __builtin_amdgcn_mfma_f32_16x16x32_bf16(a2, B2[cc][0], zacc[cc][0], 0, 0, 0);
      zacc[cc][1] = __builtin_amdgcn_mfma_f32_16x16x32_bf16(a2, B2[cc][1], zacc[cc][1], 0, 0, 0);
    }
  }
  lgkm_barrier();  // all X3s reads done; reuse [0,51200) as zs f32 [32][400]
  float* zs = (float*)smem;
  const __bf16* xbp = xbf + (size_t)n * kC * kTV;
  float4* yg4 = (float4*)(y + (size_t)n * kC * kTV);
#pragma unroll
  for (int h = 0; h < 2; ++h) {
    if ((w >> 2) == h) {
      int c0l = (w & 3) * 8;
#pragma unroll
      for (int cc = 0; cc < 8; ++cc)
#pragma unroll
        for (int vt = 0; vt < 2; ++vt) {
          int v = vt * 16 + l15;
          if (v < 25) {
#pragma unroll
            for (int jj = 0; jj < 4; ++jj)
              zs[(c0l + cc) * 400 + (g * 4 + jj) * 25 + v] = zacc[cc][vt][jj];
          }
        }
    }
    lgkm_barrier();
    for (int i4 = tid; i4 < 3200; i4 += 512) {
      int cl = i4 / 100, r4 = i4 % 100, c = h * 32 + cl;
      bf16x4v xv = *(const bf16x4v*)(xbp + (size_t)c * kTV + tb * 400 + r4 * 4);
      f32x4 zv = *(const f32x4*)(zs + cl * 400 + r4 * 4);
      float4 o;
      o.x = fmaxf(zv[0] + (float)xv[0], 0.f);
      o.y = fmaxf(zv[1] + (float)xv[1], 0.f);
      o.z = fmaxf(zv[2] + (float)xv[2], 0.f);
      o.w = fmaxf(zv[3] + (float)xv[3], 0.f);
      yg4[c * 3200 + tb * 100 + r4] = o;
    }
    lgkm_barrier();
  }
}

extern "C" void kernel_launch(void* const* d_in, const int* in_sizes, int n_in,
                              void* d_out, int out_size, void* d_ws, size_t ws_size,
                              hipStream_t stream) {
  const float* x = (const float*)d_in[0];
  const float* Ag = (const float*)d_in[1];
  const float* alpha = (const float*)d_in[2];
  const float* w1 = (const float*)d_in[3];
  const float* b1 = (const float*)d_in[4];
  const float* w2 = (const float*)d_in[5];
  const float* b2 = (const float*)d_in[6];
  const float* w3 = (const float*)d_in[7];
  const float* b3 = (const float*)d_in[8];
  const float* w4 = (const float*)d_in[9];
  const float* b4 = (const float*)d_in[10];
  const int* sparse = (const int*)d_in[11];

  unsigned char* ws = (unsigned char*)d_ws;
  float* xm = (float*)ws;  // [16][64][25] f32 at offset 0
  __bf16* xbf = (__bf16*)(ws + WS_XBF);
  float* y = (float*)d_out;

  hipFuncSetAttribute((const void*)k3_main,
                      hipFuncAttributeMaxDynamicSharedMemorySize, 73728);

  k1_cvt<<<kN * kC, 256, 0, stream>>>(x, xbf, xm);
  k2_attn<<<kS * kN * 4, 256, 0, stream>>>(xm, Ag, alpha, w1, b1, w2, b2, w3, w4,
                                           b4, sparse, ws);
  dim3 g3(kN, kT / 16);
  k3_main<<<g3, 512, 73728, stream>>>(xbf, b3, ws, y);
}